// Round 6
// baseline (358.610 us; speedup 1.0000x reference)
//
#include <hip/hip_runtime.h>
#include <stdint.h>

#define T_TOKENS 4096
#define HID 1024
#define FFN 2048
#define NE 8

typedef __attribute__((ext_vector_type(8))) short bf16x8;
typedef __attribute__((ext_vector_type(4))) float f32x4;

__device__ __forceinline__ unsigned short f2bf(float f) {
  union { float f; uint32_t u; } v; v.f = f;
  uint32_t r = v.u + 0x7FFFu + ((v.u >> 16) & 1u);
  return (unsigned short)(r >> 16);
}

__device__ __forceinline__ uint32_t pack2(float a, float b) {
  return (uint32_t)f2bf(a) | ((uint32_t)f2bf(b) << 16);
}

__device__ __forceinline__ void gload16(const unsigned short* g, unsigned short* l) {
  __builtin_amdgcn_global_load_lds(
      (const __attribute__((address_space(1))) void*)(g),
      (__attribute__((address_space(3))) void*)(l), 16, 0, 0);
}

// XOR chunk swizzle: tile [128 rows][32 k] bf16, 4x16B chunks per row.
// stored chunk s = g ^ ((r>>1)&3) => 16B-slot bijective over 8 consecutive rows.
__device__ __forceinline__ int frag_off(int r, int g) {
  return r * 32 + ((g ^ ((r >> 1) & 3)) << 3);
}

// ---- ws layout ----
constexpr size_t XBF_OFF  = 0;                                       // 8 MB
constexpr size_t HBUF_OFF = (size_t)T_TOKENS * HID * 2;              // 32 MB
constexpr size_t TOKE_OFF = HBUF_OFF + (size_t)T_TOKENS * 2 * FFN * 2;
constexpr size_t TOKW_OFF = TOKE_OFF + (size_t)T_TOKENS * 2 * 4;
constexpr size_t CNT_OFF  = TOKW_OFF + (size_t)T_TOKENS * 2 * 4;
constexpr size_t OFF_OFF  = CNT_OFF + 64;
constexpr size_t LIST_OFF = OFF_OFF + 64;
constexpr size_t META_END = LIST_OFF + (size_t)NE * T_TOKENS * 4;    // ~40.2 MB
constexpr size_t W1BF_OFF = META_END;                                // 32 MB
constexpr size_t V1BF_OFF = W1BF_OFF + (size_t)NE * FFN * HID * 2;   // 32 MB
constexpr size_t W2T_OFF  = V1BF_OFF + (size_t)NE * FFN * HID * 2;   // 32 MB
constexpr size_t WS_BIG   = W2T_OFF + (size_t)NE * HID * FFN * 2;    // ~136.2 MB

// ---- generic fp32 -> bf16 cast (8 elems / thread, exact grid) ----
__global__ __launch_bounds__(256) void cast_f32_bf16_kernel(const float* __restrict__ src,
                                                            unsigned short* __restrict__ dst) {
  size_t i = (size_t)blockIdx.x * 256 + threadIdx.x;
  const float4* sv = (const float4*)src;
  float4 a = sv[i * 2], b = sv[i * 2 + 1];
  uint4 o;
  o.x = pack2(a.x, a.y); o.y = pack2(a.z, a.w);
  o.z = pack2(b.x, b.y); o.w = pack2(b.z, b.w);
  ((uint4*)dst)[i] = o;
}

// fused cast of w1 and v1 (one launch)
__global__ __launch_bounds__(256) void cast_w1v1_kernel(const float* __restrict__ w1,
                                                        const float* __restrict__ v1,
                                                        unsigned short* __restrict__ w1b,
                                                        unsigned short* __restrict__ v1b) {
  constexpr size_t HALF = (size_t)NE * FFN * HID / 8 / 256;  // blocks per tensor
  const float* src = (blockIdx.x < HALF) ? w1 : v1;
  unsigned short* dst = (blockIdx.x < HALF) ? w1b : v1b;
  size_t bi = (blockIdx.x < HALF) ? blockIdx.x : blockIdx.x - HALF;
  size_t i = bi * 256 + threadIdx.x;
  const float4* sv = (const float4*)src;
  float4 a = sv[i * 2], b = sv[i * 2 + 1];
  uint4 o;
  o.x = pack2(a.x, a.y); o.y = pack2(a.z, a.w);
  o.z = pack2(b.x, b.y); o.w = pack2(b.z, b.w);
  ((uint4*)dst)[i] = o;
}

// ---- transpose-cast w2 [E][FFN][HID] f32 -> w2t [E][HID][FFN] bf16 ----
__global__ __launch_bounds__(256) void transpose_cast_w2_kernel(const float* __restrict__ w2,
                                                                unsigned short* __restrict__ w2t) {
  int nb = blockIdx.x;   // HID/64
  int kb = blockIdx.y;   // FFN/64
  int e  = blockIdx.z;
  __shared__ unsigned short s[64][68];
  int t = threadIdx.x;
  int tr = t >> 4, tc = (t & 15) * 4;
  const float* src = w2 + ((size_t)e * FFN + kb * 64) * HID + nb * 64;
#pragma unroll
  for (int i = 0; i < 4; ++i) {
    int k = tr + i * 16;
    float4 v = *(const float4*)(src + (size_t)k * HID + tc);
    s[k][tc + 0] = f2bf(v.x); s[k][tc + 1] = f2bf(v.y);
    s[k][tc + 2] = f2bf(v.z); s[k][tc + 3] = f2bf(v.w);
  }
  __syncthreads();
  int n = t >> 2, kc = (t & 3) * 16;
  unsigned short* dst = w2t + ((size_t)e * HID + nb * 64 + n) * FFN + kb * 64 + kc;
  unsigned short tmp[16];
#pragma unroll
  for (int i = 0; i < 16; ++i) tmp[i] = s[kc + i][n];
  uint4 o0, o1;
  o0.x = tmp[0] | (tmp[1] << 16);  o0.y = tmp[2] | (tmp[3] << 16);
  o0.z = tmp[4] | (tmp[5] << 16);  o0.w = tmp[6] | (tmp[7] << 16);
  o1.x = tmp[8] | (tmp[9] << 16);  o1.y = tmp[10] | (tmp[11] << 16);
  o1.z = tmp[12] | (tmp[13] << 16); o1.w = tmp[14] | (tmp[15] << 16);
  *(uint4*)dst = o0;
  *(uint4*)(dst + 8) = o1;
}

// ---- router (+ fused x->bf16 cast): logits -> softmax -> top2 -> L1 norm ----
__global__ __launch_bounds__(256) void router_kernel(const float* __restrict__ x,
                                                     const float* __restrict__ rw,
                                                     int* __restrict__ tok_e,
                                                     float* __restrict__ tok_w,
                                                     unsigned short* __restrict__ xbf) {
  __shared__ float s_rw[NE * HID];
  int tid = threadIdx.x;
  for (int i = tid; i < NE * HID / 4; i += 256)
    ((float4*)s_rw)[i] = ((const float4*)rw)[i];
  __syncthreads();
  int wave = tid >> 6, lane = tid & 63;
  int t = blockIdx.x * 4 + wave;
  const float* xr = x + (size_t)t * HID;
  unsigned short* xbr = xbf + (size_t)t * HID;
  float acc[NE];
#pragma unroll
  for (int e = 0; e < NE; ++e) acc[e] = 0.0f;
  for (int c = 0; c < HID / 64; ++c) {
    int idx = c * 64 + lane;
    float xv = xr[idx];
    xbr[idx] = f2bf(xv);        // fused cast (every token routed => full coverage)
#pragma unroll
    for (int e = 0; e < NE; ++e) acc[e] += xv * s_rw[e * HID + idx];
  }
#pragma unroll
  for (int e = 0; e < NE; ++e)
    for (int off = 32; off > 0; off >>= 1) acc[e] += __shfl_down(acc[e], off);
  if (lane == 0) {
    float m = acc[0];
#pragma unroll
    for (int e = 1; e < NE; ++e) m = fmaxf(m, acc[e]);
    float p[NE], Z = 0.0f;
#pragma unroll
    for (int e = 0; e < NE; ++e) { p[e] = expf(acc[e] - m); Z += p[e]; }
    int e0 = 0;
#pragma unroll
    for (int e = 1; e < NE; ++e) if (p[e] > p[e0]) e0 = e;
    int e1 = (e0 == 0) ? 1 : 0;
#pragma unroll
    for (int e = 0; e < NE; ++e) if (e != e0 && p[e] > p[e1]) e1 = e;
    float w0 = p[e0] / Z, w1 = p[e1] / Z;
    float nrm = w0 + w1;  // P_NORM = 1, weights positive
    tok_e[t * 2] = e0; tok_e[t * 2 + 1] = e1;
    tok_w[t * 2] = w0 / nrm; tok_w[t * 2 + 1] = w1 / nrm;
  }
}

// ---- scatter pairs into per-expert lists ----
__global__ __launch_bounds__(256) void scatter_kernel(const int* __restrict__ tok_e,
                                                      int* __restrict__ counts,
                                                      int* __restrict__ lists) {
  int p = blockIdx.x * 256 + threadIdx.x;
  if (p < T_TOKENS * 2) {
    int e = tok_e[p];
    int pos = atomicAdd(&counts[e], 1);
    lists[e * T_TOKENS + pos] = p;
  }
}

__global__ void offsets_kernel(const int* __restrict__ counts, int* __restrict__ offs) {
  if (threadIdx.x == 0 && blockIdx.x == 0) {
    int r = 0;
    for (int e = 0; e < NE; ++e) { offs[e] = r; r += counts[e]; }
  }
}

// ================= 2-phase pipelined GEMMs =================
// GEMM1: h = silu(x@w1^T) * (x@v1^T).
// 256 thr = 4 waves (2Mx2N), wave tile 64x64 (acc 4x4 per gemm), block 128x128.
// FLOP/LDS-byte = 42.7 (vs 32 at 64x32 waves); 32 MFMA per wave per K-step.
__global__ __launch_bounds__(256) void gemm1b_kernel(
    const unsigned short* __restrict__ xbf,
    const unsigned short* __restrict__ w1b, const unsigned short* __restrict__ v1b,
    const int* __restrict__ counts, const int* __restrict__ offs,
    const int* __restrict__ lists, unsigned short* __restrict__ hbuf) {
  constexpr int BUFSZ = 128 * 32;   // elements per slot
  constexpr int NT = HID / 32;      // 32 K-tiles (even)
  int nt = blockIdx.x, mt = blockIdx.y, e = blockIdx.z;
  int ne = counts[e];
  if (mt * 128 >= ne) return;
  __shared__ unsigned short s_a[2 * BUFSZ];
  __shared__ unsigned short s_b1[2 * BUFSZ];
  __shared__ unsigned short s_b2[2 * BUFSZ];
  int tid = threadIdx.x;
  // staging: thread owns 16B chunks tid and tid+256 of each tensor
  // chunk c -> row c>>2, slot c&3; rows r0 and r0+64 share the swizzle term
  int r0 = tid >> 2, slot = tid & 3;
  int lchunk = slot ^ ((r0 >> 1) & 3);            // same for r0+64 (64 = 0 mod 8)
  const int* lst = lists + e * T_TOKENS + mt * 128;
  int tok0 = lst[(mt * 128 + r0      < ne) ? r0      : 0] >> 1;
  int tok1 = lst[(mt * 128 + r0 + 64 < ne) ? r0 + 64 : 0] >> 1;
  const unsigned short* aptr0 = xbf + (size_t)tok0 * HID + lchunk * 8;
  const unsigned short* aptr1 = xbf + (size_t)tok1 * HID + lchunk * 8;
  size_t brow0 = ((size_t)e * FFN + nt * 128 + r0)      * HID + lchunk * 8;
  size_t brow1 = ((size_t)e * FFN + nt * 128 + r0 + 64) * HID + lchunk * 8;
  const unsigned short* b1p0 = w1b + brow0;
  const unsigned short* b1p1 = w1b + brow1;
  const unsigned short* b2p0 = v1b + brow0;
  const unsigned short* b2p1 = v1b + brow1;

  int lane = tid & 63, wv = tid >> 6;
  int wm = (wv >> 1) * 64, wn = (wv & 1) * 64;    // 2Mx2N waves of 64x64
  int rl = lane & 15, g = lane >> 4;
  int aoff[4], boff[4];
#pragma unroll
  for (int m = 0; m < 4; ++m) aoff[m] = frag_off(wm + m * 16 + rl, g);
#pragma unroll
  for (int n = 0; n < 4; ++n) boff[n] = frag_off(wn + n * 16 + rl, g);

  f32x4 zero = {0.0f, 0.0f, 0.0f, 0.0f};
  f32x4 acc1[4][4], acc2[4][4];
#pragma unroll
  for (int i = 0; i < 4; ++i)
#pragma unroll
    for (int j = 0; j < 4; ++j) { acc1[i][j] = zero; acc2[i][j] = zero; }

  auto stage = [&](int s, int t) {   // s literal -> const-folded LDS bases
    int off = t * 32;
    unsigned short* base_a  = s_a  + s * BUFSZ;
    unsigned short* base_b1 = s_b1 + s * BUFSZ;
    unsigned short* base_b2 = s_b2 + s * BUFSZ;
    gload16(aptr0 + off, base_a  + tid * 8);
    gload16(aptr1 + off, base_a  + (tid + 256) * 8);
    gload16(b1p0  + off, base_b1 + tid * 8);
    gload16(b1p1  + off, base_b1 + (tid + 256) * 8);
    gload16(b2p0  + off, base_b2 + tid * 8);
    gload16(b2p1  + off, base_b2 + (tid + 256) * 8);
  };
  auto compute = [&](int s) {
    const unsigned short* pa  = s_a  + s * BUFSZ;
    const unsigned short* pb1 = s_b1 + s * BUFSZ;
    const unsigned short* pb2 = s_b2 + s * BUFSZ;
    bf16x8 af[4], bfr1[4], bfr2[4];
#pragma unroll
    for (int m = 0; m < 4; ++m) af[m] = *(const bf16x8*)(pa + aoff[m]);
#pragma unroll
    for (int n = 0; n < 4; ++n) {
      bfr1[n] = *(const bf16x8*)(pb1 + boff[n]);
      bfr2[n] = *(const bf16x8*)(pb2 + boff[n]);
    }
#pragma unroll
    for (int m = 0; m < 4; ++m)
#pragma unroll
      for (int n = 0; n < 4; ++n) {
        acc1[m][n] = __builtin_amdgcn_mfma_f32_16x16x32_bf16(af[m], bfr1[n], acc1[m][n], 0, 0, 0);
        acc2[m][n] = __builtin_amdgcn_mfma_f32_16x16x32_bf16(af[m], bfr2[n], acc2[m][n], 0, 0, 0);
      }
  };

  stage(0, 0);
  __syncthreads();
  for (int t = 0; t < NT; t += 2) {
    stage(1, t + 1);                 // NT even: t+1 <= NT-1 always valid
    compute(0);
    __syncthreads();
    if (t + 2 < NT) stage(0, t + 2);
    compute(1);
    __syncthreads();
  }

  int hb = offs[e];
#pragma unroll
  for (int m = 0; m < 4; ++m) {
#pragma unroll
    for (int j = 0; j < 4; ++j) {
      int r = mt * 128 + wm + m * 16 + (lane >> 4) * 4 + j;
      if (r < ne) {
        size_t rowo = (size_t)(hb + r) * FFN;
#pragma unroll
        for (int n = 0; n < 4; ++n) {
          int col = nt * 128 + wn + n * 16 + rl;
          float c1 = acc1[m][n][j], c2 = acc2[m][n][j];
          float h = c1 / (1.0f + __expf(-c1)) * c2;
          hbuf[rowo + col] = f2bf(h);
        }
      }
    }
  }
}

// GEMM2: out += (h @ w2) * combine_weight; B from pre-transposed w2t [E][HID][FFN].
// (unchanged from round 5: 512 thr, 2Mx4N waves of 64x32)
__global__ __launch_bounds__(512) void gemm2b_kernel(
    const unsigned short* __restrict__ hbuf, const unsigned short* __restrict__ w2t,
    const int* __restrict__ counts, const int* __restrict__ offs,
    const int* __restrict__ lists, const float* __restrict__ tok_w,
    float* __restrict__ out) {
  constexpr int BUFSZ = 128 * 32;
  constexpr int NT = FFN / 32;      // 64 K-tiles (even)
  int nt = blockIdx.x, mt = blockIdx.y, e = blockIdx.z;
  int ne = counts[e];
  if (mt * 128 >= ne) return;
  __shared__ unsigned short s_a[2 * BUFSZ];
  __shared__ unsigned short s_b[2 * BUFSZ];
  int tid = threadIdx.x;
  int hb = offs[e];
  int srow = tid >> 2, slot = tid & 3;
  int lchunk = slot ^ ((srow >> 1) & 3);
  int ar = mt * 128 + ((mt * 128 + srow < ne) ? srow : 0);
  const unsigned short* aptr = hbuf + (size_t)(hb + ar) * FFN + lchunk * 8;
  const unsigned short* bptr = w2t + ((size_t)e * HID + nt * 128 + srow) * FFN + lchunk * 8;

  int lane = tid & 63, wv = tid >> 6;
  int wm = (wv >> 2) * 64, wn = (wv & 3) * 32;
  int rl = lane & 15, g = lane >> 4;
  int aoff[4], boff[2];
#pragma unroll
  for (int m = 0; m < 4; ++m) aoff[m] = frag_off(wm + m * 16 + rl, g);
#pragma unroll
  for (int n = 0; n < 2; ++n) boff[n] = frag_off(wn + n * 16 + rl, g);

  f32x4 zero = {0.0f, 0.0f, 0.0f, 0.0f};
  f32x4 acc[4][2];
#pragma unroll
  for (int i = 0; i < 4; ++i)
#pragma unroll
    for (int j = 0; j < 2; ++j) acc[i][j] = zero;

  auto stage = [&](int s, int t) {
    int off = t * 32;
    gload16(aptr + off, s_a + s * BUFSZ + tid * 8);
    gload16(bptr + off, s_b + s * BUFSZ + tid * 8);
  };
  auto compute = [&](int s) {
    const unsigned short* pa = s_a + s * BUFSZ;
    const unsigned short* pb = s_b + s * BUFSZ;
    bf16x8 af[4], bfr[2];
#pragma unroll
    for (int m = 0; m < 4; ++m) af[m] = *(const bf16x8*)(pa + aoff[m]);
#pragma unroll
    for (int n = 0; n < 2; ++n) bfr[n] = *(const bf16x8*)(pb + boff[n]);
#pragma unroll
    for (int m = 0; m < 4; ++m)
#pragma unroll
      for (int n = 0; n < 2; ++n)
        acc[m][n] = __builtin_amdgcn_mfma_f32_16x16x32_bf16(af[m], bfr[n], acc[m][n], 0, 0, 0);
  };

  stage(0, 0);
  __syncthreads();
  for (int t = 0; t < NT; t += 2) {
    stage(1, t + 1);
    compute(0);
    __syncthreads();
    if (t + 2 < NT) stage(0, t + 2);
    compute(1);
    __syncthreads();
  }

#pragma unroll
  for (int m = 0; m < 4; ++m) {
#pragma unroll
    for (int j = 0; j < 4; ++j) {
      int r = mt * 128 + wm + m * 16 + (lane >> 4) * 4 + j;
      if (r < ne) {
        int p = lists[e * T_TOKENS + r];
        float w = tok_w[p];
        float* orow = out + (size_t)(p >> 1) * HID;
#pragma unroll
        for (int n = 0; n < 2; ++n) {
          int col = nt * 128 + wn + n * 16 + rl;
          atomicAdd(orow + col, acc[m][n][j] * w);  // exactly 2 adds/address
        }
      }
    }
  }
}

// ================= fallback path (ws too small): proven round-2 kernels ======

__global__ __launch_bounds__(512) void gemm1_kernel(
    const unsigned short* __restrict__ xbf,
    const float* __restrict__ w1, const float* __restrict__ v1,
    const int* __restrict__ counts, const int* __restrict__ offs,
    const int* __restrict__ lists, unsigned short* __restrict__ hbuf) {
  int nt = blockIdx.x, mt = blockIdx.y, e = blockIdx.z;
  int ne = counts[e];
  if (mt * 128 >= ne) return;
  int nrows = ne - mt * 128; if (nrows > 128) nrows = 128;
  __shared__ unsigned short s_a[128 * 40];
  __shared__ unsigned short s_b1[128 * 40];
  __shared__ unsigned short s_b2[128 * 40];
  const int* lst = lists + e * T_TOKENS + mt * 128;
  int tid = threadIdx.x;
  int sr = tid >> 2, sc = tid & 3;
  int pr = lst[(sr < nrows) ? sr : 0];
  const unsigned short* asrc = xbf + (size_t)(pr >> 1) * HID + sc * 8;
  size_t brow = ((size_t)e * FFN + nt * 128 + sr) * HID + sc * 8;
  const float* b1s = w1 + brow;
  const float* b2s = v1 + brow;
  int lane = tid & 63, wv = tid >> 6;
  int wm = (wv >> 2) * 64, wn = (wv & 3) * 32;
  int rl = lane & 15, kg = (lane >> 4) * 8;
  f32x4 zero = {0.0f, 0.0f, 0.0f, 0.0f};
  f32x4 acc1[4][2], acc2[4][2];
#pragma unroll
  for (int i = 0; i < 4; ++i)
#pragma unroll
    for (int j = 0; j < 2; ++j) { acc1[i][j] = zero; acc2[i][j] = zero; }
  int sdst = sr * 40 + sc * 8;
  for (int kk = 0; kk < HID; kk += 32) {
    uint4 av = *(const uint4*)(asrc + kk);
    float4 f0 = *(const float4*)(b1s + kk);
    float4 f1 = *(const float4*)(b1s + kk + 4);
    float4 g0 = *(const float4*)(b2s + kk);
    float4 g1 = *(const float4*)(b2s + kk + 4);
    *(uint4*)(s_a + sdst) = av;
    uint4 bv; bv.x = pack2(f0.x, f0.y); bv.y = pack2(f0.z, f0.w);
    bv.z = pack2(f1.x, f1.y); bv.w = pack2(f1.z, f1.w);
    *(uint4*)(s_b1 + sdst) = bv;
    uint4 cv; cv.x = pack2(g0.x, g0.y); cv.y = pack2(g0.z, g0.w);
    cv.z = pack2(g1.x, g1.y); cv.w = pack2(g1.z, g1.w);
    *(uint4*)(s_b2 + sdst) = cv;
    __syncthreads();
    bf16x8 af[4], bf1[2], bf2[2];
#pragma unroll
    for (int m = 0; m < 4; ++m)
      af[m] = *(const bf16x8*)(s_a + (wm + m * 16 + rl) * 40 + kg);
#pragma unroll
    for (int n = 0; n < 2; ++n) {
      bf1[n] = *(const bf16x8*)(s_b1 + (wn + n * 16 + rl) * 40 + kg);
      bf2[n] = *(const bf16x8*)(s_b2 + (wn + n * 16 + rl) * 40 + kg);
    }
#pragma unroll
    for (int m = 0; m < 4; ++m)
#pragma unroll
      for (int n = 0; n < 2; ++n) {
        acc1[m][n] = __builtin_amdgcn_mfma_f32_16x16x32_bf16(af[m], bf1[n], acc1[m][n], 0, 0, 0);
        acc2[m][n] = __builtin_amdgcn_mfma_f32_16x16x32_bf16(af[m], bf2[n], acc2[m][n], 0, 0, 0);
      }
    __syncthreads();
  }
  int hb = offs[e];
#pragma unroll
  for (int m = 0; m < 4; ++m) {
#pragma unroll
    for (int j = 0; j < 4; ++j) {
      int r = mt * 128 + wm + m * 16 + (lane >> 4) * 4 + j;
      if (r < ne) {
        size_t rowo = (size_t)(hb + r) * FFN;
#pragma unroll
        for (int n = 0; n < 2; ++n) {
          int col = nt * 128 + wn + n * 16 + rl;
          float c1 = acc1[m][n][j], c2 = acc2[m][n][j];
          float h = c1 / (1.0f + __expf(-c1)) * c2;
          hbuf[rowo + col] = f2bf(h);
        }
      }
    }
  }
}

__global__ __launch_bounds__(512) void gemm2_kernel(
    const unsigned short* __restrict__ hbuf, const float* __restrict__ w2,
    const int* __restrict__ counts, const int* __restrict__ offs,
    const int* __restrict__ lists, const float* __restrict__ tok_w,
    float* __restrict__ out) {
  int nt = blockIdx.x, mt = blockIdx.y, e = blockIdx.z;
  int ne = counts[e];
  if (mt * 128 >= ne) return;
  int nrows = ne - mt * 128; if (nrows > 128) nrows = 128;
  __shared__ unsigned short s_a[128 * 40];
  __shared__ unsigned short s_b[128 * 40];
  int tid = threadIdx.x;
  int hb = offs[e];
  int sr = tid >> 2, sc = tid & 3;
  int ar = mt * 128 + ((sr < nrows) ? sr : 0);
  const unsigned short* asrc = hbuf + (size_t)(hb + ar) * FFN + sc * 8;
  int bk = tid >> 4, bn = tid & 15;
  const float* bsrc = w2 + ((size_t)e * FFN + bk) * HID + nt * 128 + bn;
  int lane = tid & 63, wv = tid >> 6;
  int wm = (wv >> 2) * 64, wn = (wv & 3) * 32;
  int rl = lane & 15, kg = (lane >> 4) * 8;
  f32x4 zero = {0.0f, 0.0f, 0.0f, 0.0f};
  f32x4 acc[4][2];
#pragma unroll
  for (int i = 0; i < 4; ++i)
#pragma unroll
    for (int j = 0; j < 2; ++j) acc[i][j] = zero;
  int sdst = sr * 40 + sc * 8;
  for (int kk = 0; kk < FFN; kk += 32) {
    uint4 av = *(const uint4*)(asrc + kk);
    const float* bs = bsrc + (size_t)kk * HID;
    float bvals[8];
#pragma unroll
    for (int i = 0; i < 8; ++i) bvals[i] = bs[i * 16];
    *(uint4*)(s_a + sdst) = av;
#pragma unroll
    for (int i = 0; i < 8; ++i) s_b[(bn + i * 16) * 40 + bk] = f2bf(bvals[i]);
    __syncthreads();
    bf16x8 af[4], bfr[2];
#pragma unroll
    for (int m = 0; m < 4; ++m)
      af[m] = *(const bf16x8*)(s_a + (wm + m * 16 + rl) * 40 + kg);
#pragma unroll
    for (int n = 0; n < 2; ++n)
      bfr[n] = *(const bf16x8*)(s_b + (wn + n * 16 + rl) * 40 + kg);
#pragma unroll
    for (int m = 0; m < 4; ++m)
#pragma unroll
      for (int n = 0; n < 2; ++n)
        acc[m][n] = __builtin_amdgcn_mfma_f32_16x16x32_bf16(af[m], bfr[n], acc[m][n], 0, 0, 0);
    __syncthreads();
  }
#pragma unroll
  for (int m = 0; m < 4; ++m) {
#pragma unroll
    for (int j = 0; j < 4; ++j) {
      int r = mt * 128 + wm + m * 16 + (lane >> 4) * 4 + j;
      if (r < ne) {
        int p = lists[e * T_TOKENS + r];
        float w = tok_w[p];
        float* orow = out + (size_t)(p >> 1) * HID;
#pragma unroll
        for (int n = 0; n < 2; ++n) {
          int col = nt * 128 + wn + n * 16 + rl;
          atomicAdd(orow + col, acc[m][n][j] * w);
        }
      }
    }
  }
}

extern "C" void kernel_launch(void* const* d_in, const int* in_sizes, int n_in,
                              void* d_out, int out_size, void* d_ws, size_t ws_size,
                              hipStream_t stream) {
  const float* x  = (const float*)d_in[0];
  const float* rw = (const float*)d_in[1];
  const float* w1 = (const float*)d_in[2];
  const float* v1 = (const float*)d_in[3];
  const float* w2 = (const float*)d_in[4];
  float* out = (float*)d_out;
  char* ws = (char*)d_ws;
  if (ws_size < META_END) return;

  unsigned short* xbf  = (unsigned short*)(ws + XBF_OFF);
  unsigned short* hbuf = (unsigned short*)(ws + HBUF_OFF);
  int*   tok_e  = (int*)(ws + TOKE_OFF);
  float* tok_w  = (float*)(ws + TOKW_OFF);
  int*   counts = (int*)(ws + CNT_OFF);
  int*   offs   = (int*)(ws + OFF_OFF);
  int*   lists  = (int*)(ws + LIST_OFF);

  hipMemsetAsync(d_out, 0, (size_t)T_TOKENS * HID * 4, stream);
  hipMemsetAsync(counts, 0, NE * sizeof(int), stream);

  router_kernel<<<T_TOKENS / 4, 256, 0, stream>>>(x, rw, tok_e, tok_w, xbf);
  scatter_kernel<<<(T_TOKENS * 2 + 255) / 256, 256, 0, stream>>>(tok_e, counts, lists);
  offsets_kernel<<<1, 64, 0, stream>>>(counts, offs);

  if (ws_size >= WS_BIG) {
    unsigned short* w1b = (unsigned short*)(ws + W1BF_OFF);
    unsigned short* v1b = (unsigned short*)(ws + V1BF_OFF);
    unsigned short* w2t = (unsigned short*)(ws + W2T_OFF);
    int wblocks = NE * FFN * HID / 8 / 256;
    cast_w1v1_kernel<<<2 * wblocks, 256, 0, stream>>>(w1, v1, w1b, v1b);
    transpose_cast_w2_kernel<<<dim3(HID / 64, FFN / 64, NE), 256, 0, stream>>>(w2, w2t);
    gemm1b_kernel<<<dim3(FFN / 128, T_TOKENS / 128, NE), 256, 0, stream>>>(
        xbf, w1b, v1b, counts, offs, lists, hbuf);
    gemm2b_kernel<<<dim3(HID / 128, T_TOKENS / 128, NE), 512, 0, stream>>>(
        hbuf, w2t, counts, offs, lists, tok_w, out);
  } else {
    gemm1_kernel<<<dim3(FFN / 128, T_TOKENS / 128, NE), 512, 0, stream>>>(
        xbf, w1, v1, counts, offs, lists, hbuf);
    gemm2_kernel<<<dim3(HID / 128, T_TOKENS / 128, NE), 512, 0, stream>>>(
        hbuf, w2, counts, offs, lists, tok_w, out);
  }
}

// Round 7
// 287.177 us; speedup vs baseline: 1.2487x; 1.2487x over previous
//
#include <hip/hip_runtime.h>
#include <stdint.h>

#define T_TOKENS 4096
#define HID 1024
#define FFN 2048
#define NE 8

typedef __attribute__((ext_vector_type(8))) short bf16x8;
typedef __attribute__((ext_vector_type(4))) float f32x4;

__device__ __forceinline__ unsigned short f2bf(float f) {
  union { float f; uint32_t u; } v; v.f = f;
  uint32_t r = v.u + 0x7FFFu + ((v.u >> 16) & 1u);
  return (unsigned short)(r >> 16);
}

__device__ __forceinline__ uint32_t pack2(float a, float b) {
  return (uint32_t)f2bf(a) | ((uint32_t)f2bf(b) << 16);
}

__device__ __forceinline__ void gload16(const unsigned short* g, unsigned short* l) {
  __builtin_amdgcn_global_load_lds(
      (const __attribute__((address_space(1))) void*)(g),
      (__attribute__((address_space(3))) void*)(l), 16, 0, 0);
}

// XOR chunk swizzle: tile [128 rows][32 k] bf16, 4x16B chunks per row.
// stored chunk s = g ^ ((r>>1)&3) => 16B-slot bijective over 8 consecutive rows.
__device__ __forceinline__ int frag_off(int r, int g) {
  return r * 32 + ((g ^ ((r >> 1) & 3)) << 3);
}

// ---- ws layout ----
constexpr size_t XBF_OFF  = 0;                                       // 8 MB
constexpr size_t HBUF_OFF = (size_t)T_TOKENS * HID * 2;              // 32 MB
constexpr size_t TOKE_OFF = HBUF_OFF + (size_t)T_TOKENS * 2 * FFN * 2;
constexpr size_t TOKW_OFF = TOKE_OFF + (size_t)T_TOKENS * 2 * 4;
constexpr size_t CNT_OFF  = TOKW_OFF + (size_t)T_TOKENS * 2 * 4;
constexpr size_t OFF_OFF  = CNT_OFF + 64;
constexpr size_t LIST_OFF = OFF_OFF + 64;
constexpr size_t META_END = LIST_OFF + (size_t)NE * T_TOKENS * 4;    // ~40.2 MB
constexpr size_t W1BF_OFF = META_END;                                // 32 MB (ybuf reuses this)
constexpr size_t V1BF_OFF = W1BF_OFF + (size_t)NE * FFN * HID * 2;   // 32 MB
constexpr size_t W2T_OFF  = V1BF_OFF + (size_t)NE * FFN * HID * 2;   // 32 MB
constexpr size_t WS_BIG   = W2T_OFF + (size_t)NE * HID * FFN * 2;    // ~136.2 MB
// ybuf: [8192 pairs][HID] fp32 = 32 MB, overlaps w1b (dead after gemm1b).
constexpr size_t YBUF_OFF = W1BF_OFF;

// fused cast of w1 and v1 (one launch)
__global__ __launch_bounds__(256) void cast_w1v1_kernel(const float* __restrict__ w1,
                                                        const float* __restrict__ v1,
                                                        unsigned short* __restrict__ w1b,
                                                        unsigned short* __restrict__ v1b) {
  constexpr size_t HALF = (size_t)NE * FFN * HID / 8 / 256;  // blocks per tensor
  const float* src = (blockIdx.x < HALF) ? w1 : v1;
  unsigned short* dst = (blockIdx.x < HALF) ? w1b : v1b;
  size_t bi = (blockIdx.x < HALF) ? blockIdx.x : blockIdx.x - HALF;
  size_t i = bi * 256 + threadIdx.x;
  const float4* sv = (const float4*)src;
  float4 a = sv[i * 2], b = sv[i * 2 + 1];
  uint4 o;
  o.x = pack2(a.x, a.y); o.y = pack2(a.z, a.w);
  o.z = pack2(b.x, b.y); o.w = pack2(b.z, b.w);
  ((uint4*)dst)[i] = o;
}

// ---- transpose-cast w2 [E][FFN][HID] f32 -> w2t [E][HID][FFN] bf16 ----
__global__ __launch_bounds__(256) void transpose_cast_w2_kernel(const float* __restrict__ w2,
                                                                unsigned short* __restrict__ w2t) {
  int nb = blockIdx.x;   // HID/64
  int kb = blockIdx.y;   // FFN/64
  int e  = blockIdx.z;
  __shared__ unsigned short s[64][68];
  int t = threadIdx.x;
  int tr = t >> 4, tc = (t & 15) * 4;
  const float* src = w2 + ((size_t)e * FFN + kb * 64) * HID + nb * 64;
#pragma unroll
  for (int i = 0; i < 4; ++i) {
    int k = tr + i * 16;
    float4 v = *(const float4*)(src + (size_t)k * HID + tc);
    s[k][tc + 0] = f2bf(v.x); s[k][tc + 1] = f2bf(v.y);
    s[k][tc + 2] = f2bf(v.z); s[k][tc + 3] = f2bf(v.w);
  }
  __syncthreads();
  int n = t >> 2, kc = (t & 3) * 16;
  unsigned short* dst = w2t + ((size_t)e * HID + nb * 64 + n) * FFN + kb * 64 + kc;
  unsigned short tmp[16];
#pragma unroll
  for (int i = 0; i < 16; ++i) tmp[i] = s[kc + i][n];
  uint4 o0, o1;
  o0.x = tmp[0] | (tmp[1] << 16);  o0.y = tmp[2] | (tmp[3] << 16);
  o0.z = tmp[4] | (tmp[5] << 16);  o0.w = tmp[6] | (tmp[7] << 16);
  o1.x = tmp[8] | (tmp[9] << 16);  o1.y = tmp[10] | (tmp[11] << 16);
  o1.z = tmp[12] | (tmp[13] << 16); o1.w = tmp[14] | (tmp[15] << 16);
  *(uint4*)dst = o0;
  *(uint4*)(dst + 8) = o1;
}

// ---- router (+ fused x->bf16 cast): logits -> softmax -> top2 -> L1 norm ----
__global__ __launch_bounds__(256) void router_kernel(const float* __restrict__ x,
                                                     const float* __restrict__ rw,
                                                     int* __restrict__ tok_e,
                                                     float* __restrict__ tok_w,
                                                     unsigned short* __restrict__ xbf) {
  __shared__ float s_rw[NE * HID];
  int tid = threadIdx.x;
  for (int i = tid; i < NE * HID / 4; i += 256)
    ((float4*)s_rw)[i] = ((const float4*)rw)[i];
  __syncthreads();
  int wave = tid >> 6, lane = tid & 63;
  int t = blockIdx.x * 4 + wave;
  const float* xr = x + (size_t)t * HID;
  unsigned short* xbr = xbf + (size_t)t * HID;
  float acc[NE];
#pragma unroll
  for (int e = 0; e < NE; ++e) acc[e] = 0.0f;
  for (int c = 0; c < HID / 64; ++c) {
    int idx = c * 64 + lane;
    float xv = xr[idx];
    xbr[idx] = f2bf(xv);        // fused cast (every token routed => full coverage)
#pragma unroll
    for (int e = 0; e < NE; ++e) acc[e] += xv * s_rw[e * HID + idx];
  }
#pragma unroll
  for (int e = 0; e < NE; ++e)
    for (int off = 32; off > 0; off >>= 1) acc[e] += __shfl_down(acc[e], off);
  if (lane == 0) {
    float m = acc[0];
#pragma unroll
    for (int e = 1; e < NE; ++e) m = fmaxf(m, acc[e]);
    float p[NE], Z = 0.0f;
#pragma unroll
    for (int e = 0; e < NE; ++e) { p[e] = expf(acc[e] - m); Z += p[e]; }
    int e0 = 0;
#pragma unroll
    for (int e = 1; e < NE; ++e) if (p[e] > p[e0]) e0 = e;
    int e1 = (e0 == 0) ? 1 : 0;
#pragma unroll
    for (int e = 0; e < NE; ++e) if (e != e0 && p[e] > p[e1]) e1 = e;
    float w0 = p[e0] / Z, w1 = p[e1] / Z;
    float nrm = w0 + w1;  // P_NORM = 1, weights positive
    tok_e[t * 2] = e0; tok_e[t * 2 + 1] = e1;
    tok_w[t * 2] = w0 / nrm; tok_w[t * 2 + 1] = w1 / nrm;
  }
}

// ---- scatter pairs into per-expert lists ----
__global__ __launch_bounds__(256) void scatter_kernel(const int* __restrict__ tok_e,
                                                      int* __restrict__ counts,
                                                      int* __restrict__ lists) {
  int p = blockIdx.x * 256 + threadIdx.x;
  if (p < T_TOKENS * 2) {
    int e = tok_e[p];
    int pos = atomicAdd(&counts[e], 1);
    lists[e * T_TOKENS + pos] = p;
  }
}

__global__ void offsets_kernel(const int* __restrict__ counts, int* __restrict__ offs) {
  if (threadIdx.x == 0 && blockIdx.x == 0) {
    int r = 0;
    for (int e = 0; e < NE; ++e) { offs[e] = r; r += counts[e]; }
  }
}

// ---- combine: out[t] = y[2t] + y[2t+1] (ybuf rows are pair-indexed, weighted) ----
__global__ __launch_bounds__(256) void combine_kernel(const float* __restrict__ ybuf,
                                                      float* __restrict__ out) {
  int t = blockIdx.x;
  int c = threadIdx.x;
  const float4* y0 = (const float4*)(ybuf + (size_t)(2 * t) * HID);
  const float4* y1 = (const float4*)(ybuf + (size_t)(2 * t + 1) * HID);
  float4 a = y0[c], b = y1[c];
  float4 r; r.x = a.x + b.x; r.y = a.y + b.y; r.z = a.z + b.z; r.w = a.w + b.w;
  ((float4*)(out + (size_t)t * HID))[c] = r;
}

// ================= 2-phase pipelined GEMMs (proven round-5 shape) =================
// Per step: issue stage(t+1) FIRST (slots statically named), compute(t), then one
// __syncthreads(). 512 thr = 8 waves (2Mx4N, 64x32/wave); dual acc fits VGPR budget.

// GEMM1: h = silu(x@w1^T) * (x@v1^T).
__global__ __launch_bounds__(512) void gemm1b_kernel(
    const unsigned short* __restrict__ xbf,
    const unsigned short* __restrict__ w1b, const unsigned short* __restrict__ v1b,
    const int* __restrict__ counts, const int* __restrict__ offs,
    const int* __restrict__ lists, unsigned short* __restrict__ hbuf) {
  constexpr int BUFSZ = 128 * 32;   // elements per slot
  constexpr int NT = HID / 32;      // 32 K-tiles (even)
  int nt = blockIdx.x, mt = blockIdx.y, e = blockIdx.z;
  int ne = counts[e];
  if (mt * 128 >= ne) return;
  __shared__ unsigned short s_a[2 * BUFSZ];
  __shared__ unsigned short s_b1[2 * BUFSZ];
  __shared__ unsigned short s_b2[2 * BUFSZ];
  int tid = threadIdx.x;
  int srow = tid >> 2, slot = tid & 3;
  int lchunk = slot ^ ((srow >> 1) & 3);          // inverse-swizzled global chunk
  const int* lst = lists + e * T_TOKENS + mt * 128;
  int tok = lst[(mt * 128 + srow < ne) ? srow : 0] >> 1;
  const unsigned short* aptr = xbf + (size_t)tok * HID + lchunk * 8;
  size_t brow = ((size_t)e * FFN + nt * 128 + srow) * HID + lchunk * 8;
  const unsigned short* b1p = w1b + brow;
  const unsigned short* b2p = v1b + brow;

  int lane = tid & 63, wv = tid >> 6;
  int wm = (wv >> 2) * 64, wn = (wv & 3) * 32;
  int rl = lane & 15, g = lane >> 4;
  int aoff[4], boff[2];
#pragma unroll
  for (int m = 0; m < 4; ++m) aoff[m] = frag_off(wm + m * 16 + rl, g);
#pragma unroll
  for (int n = 0; n < 2; ++n) boff[n] = frag_off(wn + n * 16 + rl, g);

  f32x4 zero = {0.0f, 0.0f, 0.0f, 0.0f};
  f32x4 acc1[4][2], acc2[4][2];
#pragma unroll
  for (int i = 0; i < 4; ++i)
#pragma unroll
    for (int j = 0; j < 2; ++j) { acc1[i][j] = zero; acc2[i][j] = zero; }

  auto stage = [&](int s, int t) {   // s literal -> const-folded LDS bases
    int off = t * 32;
    gload16(aptr + off, s_a  + s * BUFSZ + tid * 8);
    gload16(b1p  + off, s_b1 + s * BUFSZ + tid * 8);
    gload16(b2p  + off, s_b2 + s * BUFSZ + tid * 8);
  };
  auto compute = [&](int s) {
    const unsigned short* pa  = s_a  + s * BUFSZ;
    const unsigned short* pb1 = s_b1 + s * BUFSZ;
    const unsigned short* pb2 = s_b2 + s * BUFSZ;
    bf16x8 af[4], bfr1[2], bfr2[2];
#pragma unroll
    for (int m = 0; m < 4; ++m) af[m] = *(const bf16x8*)(pa + aoff[m]);
#pragma unroll
    for (int n = 0; n < 2; ++n) {
      bfr1[n] = *(const bf16x8*)(pb1 + boff[n]);
      bfr2[n] = *(const bf16x8*)(pb2 + boff[n]);
    }
#pragma unroll
    for (int m = 0; m < 4; ++m)
#pragma unroll
      for (int n = 0; n < 2; ++n) {
        acc1[m][n] = __builtin_amdgcn_mfma_f32_16x16x32_bf16(af[m], bfr1[n], acc1[m][n], 0, 0, 0);
        acc2[m][n] = __builtin_amdgcn_mfma_f32_16x16x32_bf16(af[m], bfr2[n], acc2[m][n], 0, 0, 0);
      }
  };

  stage(0, 0);
  __syncthreads();
  for (int t = 0; t < NT; t += 2) {
    stage(1, t + 1);                 // NT even: t+1 <= NT-1 always valid
    compute(0);
    __syncthreads();
    if (t + 2 < NT) stage(0, t + 2);
    compute(1);
    __syncthreads();
  }

  int hb = offs[e];
#pragma unroll
  for (int m = 0; m < 4; ++m) {
#pragma unroll
    for (int j = 0; j < 4; ++j) {
      int r = mt * 128 + wm + m * 16 + (lane >> 4) * 4 + j;
      if (r < ne) {
        size_t rowo = (size_t)(hb + r) * FFN;
#pragma unroll
        for (int n = 0; n < 2; ++n) {
          int col = nt * 128 + wn + n * 16 + rl;
          float c1 = acc1[m][n][j], c2 = acc2[m][n][j];
          float h = c1 / (1.0f + __expf(-c1)) * c2;
          hbuf[rowo + col] = f2bf(h);
        }
      }
    }
  }
}

// GEMM2: ybuf[pair] = (h @ w2) * combine_weight (plain stores, pair-indexed rows).
__global__ __launch_bounds__(512) void gemm2b_kernel(
    const unsigned short* __restrict__ hbuf, const unsigned short* __restrict__ w2t,
    const int* __restrict__ counts, const int* __restrict__ offs,
    const int* __restrict__ lists, const float* __restrict__ tok_w,
    float* __restrict__ ybuf) {
  constexpr int BUFSZ = 128 * 32;
  constexpr int NT = FFN / 32;      // 64 K-tiles (even)
  int nt = blockIdx.x, mt = blockIdx.y, e = blockIdx.z;
  int ne = counts[e];
  if (mt * 128 >= ne) return;
  __shared__ unsigned short s_a[2 * BUFSZ];
  __shared__ unsigned short s_b[2 * BUFSZ];
  int tid = threadIdx.x;
  int hb = offs[e];
  int srow = tid >> 2, slot = tid & 3;
  int lchunk = slot ^ ((srow >> 1) & 3);
  int ar = mt * 128 + ((mt * 128 + srow < ne) ? srow : 0);
  const unsigned short* aptr = hbuf + (size_t)(hb + ar) * FFN + lchunk * 8;
  const unsigned short* bptr = w2t + ((size_t)e * HID + nt * 128 + srow) * FFN + lchunk * 8;

  int lane = tid & 63, wv = tid >> 6;
  int wm = (wv >> 2) * 64, wn = (wv & 3) * 32;
  int rl = lane & 15, g = lane >> 4;
  int aoff[4], boff[2];
#pragma unroll
  for (int m = 0; m < 4; ++m) aoff[m] = frag_off(wm + m * 16 + rl, g);
#pragma unroll
  for (int n = 0; n < 2; ++n) boff[n] = frag_off(wn + n * 16 + rl, g);

  f32x4 zero = {0.0f, 0.0f, 0.0f, 0.0f};
  f32x4 acc[4][2];
#pragma unroll
  for (int i = 0; i < 4; ++i)
#pragma unroll
    for (int j = 0; j < 2; ++j) acc[i][j] = zero;

  auto stage = [&](int s, int t) {
    int off = t * 32;
    gload16(aptr + off, s_a + s * BUFSZ + tid * 8);
    gload16(bptr + off, s_b + s * BUFSZ + tid * 8);
  };
  auto compute = [&](int s) {
    const unsigned short* pa = s_a + s * BUFSZ;
    const unsigned short* pb = s_b + s * BUFSZ;
    bf16x8 af[4], bfr[2];
#pragma unroll
    for (int m = 0; m < 4; ++m) af[m] = *(const bf16x8*)(pa + aoff[m]);
#pragma unroll
    for (int n = 0; n < 2; ++n) bfr[n] = *(const bf16x8*)(pb + boff[n]);
#pragma unroll
    for (int m = 0; m < 4; ++m)
#pragma unroll
      for (int n = 0; n < 2; ++n)
        acc[m][n] = __builtin_amdgcn_mfma_f32_16x16x32_bf16(af[m], bfr[n], acc[m][n], 0, 0, 0);
  };

  stage(0, 0);
  __syncthreads();
  for (int t = 0; t < NT; t += 2) {
    stage(1, t + 1);
    compute(0);
    __syncthreads();
    if (t + 2 < NT) stage(0, t + 2);
    compute(1);
    __syncthreads();
  }

#pragma unroll
  for (int m = 0; m < 4; ++m) {
#pragma unroll
    for (int j = 0; j < 4; ++j) {
      int r = mt * 128 + wm + m * 16 + (lane >> 4) * 4 + j;
      if (r < ne) {
        int p = lists[e * T_TOKENS + r];
        float w = tok_w[p];
        float* yrow = ybuf + (size_t)p * HID;   // pair-indexed row, written once
#pragma unroll
        for (int n = 0; n < 2; ++n) {
          int col = nt * 128 + wn + n * 16 + rl;
          yrow[col] = acc[m][n][j] * w;
        }
      }
    }
  }
}

// ================= fallback path (ws too small): proven round-2 kernels ======

__global__ __launch_bounds__(512) void gemm1_kernel(
    const unsigned short* __restrict__ xbf,
    const float* __restrict__ w1, const float* __restrict__ v1,
    const int* __restrict__ counts, const int* __restrict__ offs,
    const int* __restrict__ lists, unsigned short* __restrict__ hbuf) {
  int nt = blockIdx.x, mt = blockIdx.y, e = blockIdx.z;
  int ne = counts[e];
  if (mt * 128 >= ne) return;
  int nrows = ne - mt * 128; if (nrows > 128) nrows = 128;
  __shared__ unsigned short s_a[128 * 40];
  __shared__ unsigned short s_b1[128 * 40];
  __shared__ unsigned short s_b2[128 * 40];
  const int* lst = lists + e * T_TOKENS + mt * 128;
  int tid = threadIdx.x;
  int sr = tid >> 2, sc = tid & 3;
  int pr = lst[(sr < nrows) ? sr : 0];
  const unsigned short* asrc = xbf + (size_t)(pr >> 1) * HID + sc * 8;
  size_t brow = ((size_t)e * FFN + nt * 128 + sr) * HID + sc * 8;
  const float* b1s = w1 + brow;
  const float* b2s = v1 + brow;
  int lane = tid & 63, wv = tid >> 6;
  int wm = (wv >> 2) * 64, wn = (wv & 3) * 32;
  int rl = lane & 15, kg = (lane >> 4) * 8;
  f32x4 zero = {0.0f, 0.0f, 0.0f, 0.0f};
  f32x4 acc1[4][2], acc2[4][2];
#pragma unroll
  for (int i = 0; i < 4; ++i)
#pragma unroll
    for (int j = 0; j < 2; ++j) { acc1[i][j] = zero; acc2[i][j] = zero; }
  int sdst = sr * 40 + sc * 8;
  for (int kk = 0; kk < HID; kk += 32) {
    uint4 av = *(const uint4*)(asrc + kk);
    float4 f0 = *(const float4*)(b1s + kk);
    float4 f1 = *(const float4*)(b1s + kk + 4);
    float4 g0 = *(const float4*)(b2s + kk);
    float4 g1 = *(const float4*)(b2s + kk + 4);
    *(uint4*)(s_a + sdst) = av;
    uint4 bv; bv.x = pack2(f0.x, f0.y); bv.y = pack2(f0.z, f0.w);
    bv.z = pack2(f1.x, f1.y); bv.w = pack2(f1.z, f1.w);
    *(uint4*)(s_b1 + sdst) = bv;
    uint4 cv; cv.x = pack2(g0.x, g0.y); cv.y = pack2(g0.z, g0.w);
    cv.z = pack2(g1.x, g1.y); cv.w = pack2(g1.z, g1.w);
    *(uint4*)(s_b2 + sdst) = cv;
    __syncthreads();
    bf16x8 af[4], bf1[2], bf2[2];
#pragma unroll
    for (int m = 0; m < 4; ++m)
      af[m] = *(const bf16x8*)(s_a + (wm + m * 16 + rl) * 40 + kg);
#pragma unroll
    for (int n = 0; n < 2; ++n) {
      bf1[n] = *(const bf16x8*)(s_b1 + (wn + n * 16 + rl) * 40 + kg);
      bf2[n] = *(const bf16x8*)(s_b2 + (wn + n * 16 + rl) * 40 + kg);
    }
#pragma unroll
    for (int m = 0; m < 4; ++m)
#pragma unroll
      for (int n = 0; n < 2; ++n) {
        acc1[m][n] = __builtin_amdgcn_mfma_f32_16x16x32_bf16(af[m], bf1[n], acc1[m][n], 0, 0, 0);
        acc2[m][n] = __builtin_amdgcn_mfma_f32_16x16x32_bf16(af[m], bf2[n], acc2[m][n], 0, 0, 0);
      }
    __syncthreads();
  }
  int hb = offs[e];
#pragma unroll
  for (int m = 0; m < 4; ++m) {
#pragma unroll
    for (int j = 0; j < 4; ++j) {
      int r = mt * 128 + wm + m * 16 + (lane >> 4) * 4 + j;
      if (r < ne) {
        size_t rowo = (size_t)(hb + r) * FFN;
#pragma unroll
        for (int n = 0; n < 2; ++n) {
          int col = nt * 128 + wn + n * 16 + rl;
          float c1 = acc1[m][n][j], c2 = acc2[m][n][j];
          float h = c1 / (1.0f + __expf(-c1)) * c2;
          hbuf[rowo + col] = f2bf(h);
        }
      }
    }
  }
}

__global__ __launch_bounds__(512) void gemm2_kernel(
    const unsigned short* __restrict__ hbuf, const float* __restrict__ w2,
    const int* __restrict__ counts, const int* __restrict__ offs,
    const int* __restrict__ lists, const float* __restrict__ tok_w,
    float* __restrict__ out) {
  int nt = blockIdx.x, mt = blockIdx.y, e = blockIdx.z;
  int ne = counts[e];
  if (mt * 128 >= ne) return;
  int nrows = ne - mt * 128; if (nrows > 128) nrows = 128;
  __shared__ unsigned short s_a[128 * 40];
  __shared__ unsigned short s_b[128 * 40];
  int tid = threadIdx.x;
  int hb = offs[e];
  int sr = tid >> 2, sc = tid & 3;
  int ar = mt * 128 + ((sr < nrows) ? sr : 0);
  const unsigned short* asrc = hbuf + (size_t)(hb + ar) * FFN + sc * 8;
  int bk = tid >> 4, bn = tid & 15;
  const float* bsrc = w2 + ((size_t)e * FFN + bk) * HID + nt * 128 + bn;
  int lane = tid & 63, wv = tid >> 6;
  int wm = (wv >> 2) * 64, wn = (wv & 3) * 32;
  int rl = lane & 15, kg = (lane >> 4) * 8;
  f32x4 zero = {0.0f, 0.0f, 0.0f, 0.0f};
  f32x4 acc[4][2];
#pragma unroll
  for (int i = 0; i < 4; ++i)
#pragma unroll
    for (int j = 0; j < 2; ++j) acc[i][j] = zero;
  int sdst = sr * 40 + sc * 8;
  for (int kk = 0; kk < FFN; kk += 32) {
    uint4 av = *(const uint4*)(asrc + kk);
    const float* bs = bsrc + (size_t)kk * HID;
    float bvals[8];
#pragma unroll
    for (int i = 0; i < 8; ++i) bvals[i] = bs[i * 16];
    *(uint4*)(s_a + sdst) = av;
#pragma unroll
    for (int i = 0; i < 8; ++i) s_b[(bn + i * 16) * 40 + bk] = f2bf(bvals[i]);
    __syncthreads();
    bf16x8 af[4], bfr[2];
#pragma unroll
    for (int m = 0; m < 4; ++m)
      af[m] = *(const bf16x8*)(s_a + (wm + m * 16 + rl) * 40 + kg);
#pragma unroll
    for (int n = 0; n < 2; ++n)
      bfr[n] = *(const bf16x8*)(s_b + (wn + n * 16 + rl) * 40 + kg);
#pragma unroll
    for (int m = 0; m < 4; ++m)
#pragma unroll
      for (int n = 0; n < 2; ++n)
        acc[m][n] = __builtin_amdgcn_mfma_f32_16x16x32_bf16(af[m], bfr[n], acc[m][n], 0, 0, 0);
    __syncthreads();
  }
#pragma unroll
  for (int m = 0; m < 4; ++m) {
#pragma unroll
    for (int j = 0; j < 4; ++j) {
      int r = mt * 128 + wm + m * 16 + (lane >> 4) * 4 + j;
      if (r < ne) {
        int p = lists[e * T_TOKENS + r];
        float w = tok_w[p];
        float* orow = out + (size_t)(p >> 1) * HID;
#pragma unroll
        for (int n = 0; n < 2; ++n) {
          int col = nt * 128 + wn + n * 16 + rl;
          atomicAdd(orow + col, acc[m][n][j] * w);
        }
      }
    }
  }
}

extern "C" void kernel_launch(void* const* d_in, const int* in_sizes, int n_in,
                              void* d_out, int out_size, void* d_ws, size_t ws_size,
                              hipStream_t stream) {
  const float* x  = (const float*)d_in[0];
  const float* rw = (const float*)d_in[1];
  const float* w1 = (const float*)d_in[2];
  const float* v1 = (const float*)d_in[3];
  const float* w2 = (const float*)d_in[4];
  float* out = (float*)d_out;
  char* ws = (char*)d_ws;
  if (ws_size < META_END) return;

  unsigned short* xbf  = (unsigned short*)(ws + XBF_OFF);
  unsigned short* hbuf = (unsigned short*)(ws + HBUF_OFF);
  int*   tok_e  = (int*)(ws + TOKE_OFF);
  float* tok_w  = (float*)(ws + TOKW_OFF);
  int*   counts = (int*)(ws + CNT_OFF);
  int*   offs   = (int*)(ws + OFF_OFF);
  int*   lists  = (int*)(ws + LIST_OFF);

  hipMemsetAsync(counts, 0, NE * sizeof(int), stream);

  router_kernel<<<T_TOKENS / 4, 256, 0, stream>>>(x, rw, tok_e, tok_w, xbf);
  scatter_kernel<<<(T_TOKENS * 2 + 255) / 256, 256, 0, stream>>>(tok_e, counts, lists);
  offsets_kernel<<<1, 64, 0, stream>>>(counts, offs);

  if (ws_size >= WS_BIG) {
    unsigned short* w1b = (unsigned short*)(ws + W1BF_OFF);
    unsigned short* v1b = (unsigned short*)(ws + V1BF_OFF);
    unsigned short* w2t = (unsigned short*)(ws + W2T_OFF);
    float* ybuf = (float*)(ws + YBUF_OFF);   // overlaps w1b: dead after gemm1b
    int wblocks = NE * FFN * HID / 8 / 256;
    cast_w1v1_kernel<<<2 * wblocks, 256, 0, stream>>>(w1, v1, w1b, v1b);
    transpose_cast_w2_kernel<<<dim3(HID / 64, FFN / 64, NE), 256, 0, stream>>>(w2, w2t);
    gemm1b_kernel<<<dim3(FFN / 128, T_TOKENS / 128, NE), 512, 0, stream>>>(
        xbf, w1b, v1b, counts, offs, lists, hbuf);
    gemm2b_kernel<<<dim3(HID / 128, T_TOKENS / 128, NE), 512, 0, stream>>>(
        hbuf, w2t, counts, offs, lists, tok_w, ybuf);
    combine_kernel<<<T_TOKENS, 256, 0, stream>>>(ybuf, out);
  } else {
    hipMemsetAsync(d_out, 0, (size_t)T_TOKENS * HID * 4, stream);
    gemm1_kernel<<<dim3(FFN / 128, T_TOKENS / 128, NE), 512, 0, stream>>>(
        xbf, w1, v1, counts, offs, lists, hbuf);
    gemm2_kernel<<<dim3(HID / 128, T_TOKENS / 128, NE), 512, 0, stream>>>(
        hbuf, w2, counts, offs, lists, tok_w, out);
  }
}